// Round 4
// baseline (820.947 us; speedup 1.0000x reference)
//
#include <hip/hip_runtime.h>

#define N_NODES 100000
#define N_EDGES 3200000
#define N_GRAPHS 1000
#define IN_DIM 10
#define HIDDEN 64
#define NQUADS (N_NODES / 4)

#define NRANGES 8
#define RANGE_SIZE ((N_NODES + NRANGES - 1) / NRANGES)  // 12500
#define CHUNK_EDGES 4096

#define LAYER_BLOCKS 2048

// ---------------- degree histogram ----------------
__global__ void k_deg(const int* __restrict__ col, int* __restrict__ deg) {
    int e = blockIdx.x * blockDim.x + threadIdx.x;
    if (e < N_EDGES) atomicAdd(&deg[col[e]], 1);
}

// ---------------- hierarchical exclusive scan (offsets) ----------------
__global__ __launch_bounds__(1024) void k_scan_block(const int* __restrict__ deg,
                                                     int* __restrict__ offs,
                                                     int* __restrict__ bsums) {
    __shared__ int s[1024];
    int t = threadIdx.x;
    int i = blockIdx.x * 1024 + t;
    int v = (i < N_NODES) ? deg[i] : 0;
    s[t] = v;
    __syncthreads();
    for (int d = 1; d < 1024; d <<= 1) {
        int x = (t >= d) ? s[t - d] : 0;
        __syncthreads();
        s[t] += x;
        __syncthreads();
    }
    if (i < N_NODES) offs[i] = s[t] - v;  // block-local exclusive
    if (t == 1023) bsums[blockIdx.x] = s[t];
}

__global__ __launch_bounds__(128) void k_scan_top(int* __restrict__ bsums, int nb) {
    __shared__ int s[128];
    int t = threadIdx.x;
    int v = (t < nb) ? bsums[t] : 0;
    s[t] = v;
    __syncthreads();
    for (int d = 1; d < 128; d <<= 1) {
        int x = (t >= d) ? s[t - d] : 0;
        __syncthreads();
        s[t] += x;
        __syncthreads();
    }
    if (t < nb) bsums[t] = s[t] - v;  // exclusive
}

__global__ __launch_bounds__(1024) void k_scan_add(int* __restrict__ offs,
                                                   const int* __restrict__ bsums) {
    int i = blockIdx.x * 1024 + threadIdx.x;
    if (i < N_NODES) offs[i] += bsums[blockIdx.x];
}

// ---------------- dinv ----------------
__global__ void k_dinv(const int* __restrict__ deg, float* __restrict__ dinv) {
    int n = blockIdx.x * blockDim.x + threadIdx.x;
    if (n < N_NODES) {
        int d = deg[n];
        dinv[n] = (d > 0) ? rsqrtf((float)d) : 0.f;
    }
}

// ---------------- CSR fill, XCD-range-partitioned (from R2, kept) ----------------
__global__ __launch_bounds__(256) void k_fill(const int* __restrict__ row,
                                              const int* __restrict__ col,
                                              const int* __restrict__ offs,
                                              int* __restrict__ cursor,
                                              int* __restrict__ csr_src) {
    int range = blockIdx.x & (NRANGES - 1);
    int chunk = blockIdx.x >> 3;
    int lo = range * RANGE_SIZE;
    int hi = lo + RANGE_SIZE;
    int base = chunk * CHUNK_EDGES + threadIdx.x;
#pragma unroll
    for (int k = 0; k < CHUNK_EDGES / 256; ++k) {
        int e = base + k * 256;
        if (e < N_EDGES) {
            int c = col[e];
            int r = row[e];
            if (c >= lo && c < hi) {
                int p = atomicAdd(&cursor[c], 1);
                csr_src[offs[c] + p] = r;
            }
        }
    }
}

// ---------------- prescale x by dinv into padded 16-float rows ----------------
// xs16[n][f] = f<10 ? x[n][f]*dinv[n] : 0 ; row N_NODES = zeros (gather sink)
__global__ __launch_bounds__(256) void k_prex(const float* __restrict__ x,
                                              const float* __restrict__ dinv,
                                              float* __restrict__ xs16) {
    int i = blockIdx.x * blockDim.x + threadIdx.x;
    if (i >= (N_NODES + 1) * 16) return;
    int n = i >> 4, f = i & 15;
    float v = 0.f;
    if (n < N_NODES && f < IN_DIM) v = x[n * IN_DIM + f] * dinv[n];
    xs16[i] = v;
}

// ============ layer 1: 4 nodes/wave, scalar-lane gather of 16-float rows ============
// out stored: h1s[n] = relu(dinv[n]*sum(xs16[src]) @ W1 + b1) * dinv[n]
__global__ __launch_bounds__(256) void k_layer1(const float* __restrict__ xs16,
                                                const float* __restrict__ dinv,
                                                const int* __restrict__ offs,
                                                const int* __restrict__ deg,
                                                const int* __restrict__ csr_src,
                                                const float* __restrict__ W1,
                                                const float* __restrict__ b1,
                                                float* __restrict__ h1s) {
    int lane = threadIdx.x & 63;
    int f = lane & 15;
    int gbase = lane & 48;  // group*16
    // per-lane W1 column: W1reg[k] = W1[k][lane] (k padded to 16)
    float W1reg[16];
#pragma unroll
    for (int k = 0; k < 16; ++k) W1reg[k] = (k < IN_DIM) ? W1[k * HIDDEN + lane] : 0.f;
    float b1reg = b1[lane];

    int wid = (blockIdx.x * 256 + threadIdx.x) >> 6;
    int nwaves = gridDim.x * 4;
    for (int quad = wid; quad < NQUADS; quad += nwaves) {
        int n = quad * 4 + (lane >> 4);
        int start = offs[n], dn = deg[n];
        int maxd = max(max(__shfl(dn, 0), __shfl(dn, 16)),
                       max(__shfl(dn, 32), __shfl(dn, 48)));
        float a = 0.f;
        for (int base = 0; base < maxd; base += 16) {
            int s = csr_src[start + base + f];
            s = (base + f < dn) ? s : N_NODES;  // zero row for invalid slots
#pragma unroll
            for (int jj = 0; jj < 2; ++jj) {
                float v[8];
#pragma unroll
                for (int j = 0; j < 8; ++j) {
                    int sj = __shfl(s, gbase + jj * 8 + j);
                    v[j] = xs16[sj * 16 + f];
                }
#pragma unroll
                for (int j = 0; j < 8; ++j) a += v[j];
            }
        }
        a *= dinv[n];  // target-side norm
        // dense: per node g, out[lane] = b1 + sum_k a[g][k]*W1[k][lane]
#pragma unroll
        for (int g = 0; g < 4; ++g) {
            float acc = b1reg;
#pragma unroll
            for (int k = 0; k < 16; ++k) {
                acc += __shfl(a, g * 16 + k) * W1reg[k];
            }
            int ng = quad * 4 + g;
            h1s[ng * HIDDEN + lane] = fmaxf(acc, 0.f) * dinv[ng];
        }
    }
}

// ============ layer 2: 4 nodes/wave, float4 gather, dense via LDS W ============
__global__ __launch_bounds__(256) void k_layer2(const float* __restrict__ hs,
                                                const float* __restrict__ dinv,
                                                const int* __restrict__ offs,
                                                const int* __restrict__ deg,
                                                const int* __restrict__ csr_src,
                                                const float* __restrict__ W,
                                                const float* __restrict__ b,
                                                float* __restrict__ houts) {
    __shared__ float4 sW4[HIDDEN][16];
    for (int i = threadIdx.x; i < HIDDEN * 16; i += 256) {
        int k = i >> 4, f = i & 15;
        sW4[k][f] = *(const float4*)&W[k * HIDDEN + f * 4];
    }
    __syncthreads();
    int lane = threadIdx.x & 63;
    int f = lane & 15;
    int gbase = lane & 48;
    float4 b4 = *(const float4*)&b[f * 4];

    int wid = (blockIdx.x * 256 + threadIdx.x) >> 6;
    int nwaves = gridDim.x * 4;
    for (int quad = wid; quad < NQUADS; quad += nwaves) {
        int n = quad * 4 + (lane >> 4);
        int start = offs[n], dn = deg[n];
        int maxd = max(max(__shfl(dn, 0), __shfl(dn, 16)),
                       max(__shfl(dn, 32), __shfl(dn, 48)));
        float4 acc = make_float4(0.f, 0.f, 0.f, 0.f);
        for (int base = 0; base < maxd; base += 16) {
            int s = csr_src[start + base + f];
            s = (base + f < dn) ? s : N_NODES;
#pragma unroll
            for (int jj = 0; jj < 2; ++jj) {
                float4 v[8];
#pragma unroll
                for (int j = 0; j < 8; ++j) {
                    int sj = __shfl(s, gbase + jj * 8 + j);
                    v[j] = *(const float4*)&hs[sj * HIDDEN + f * 4];
                }
#pragma unroll
                for (int j = 0; j < 8; ++j) {
                    acc.x += v[j].x; acc.y += v[j].y; acc.z += v[j].z; acc.w += v[j].w;
                }
            }
        }
        float di = dinv[n];
        acc.x *= di; acc.y *= di; acc.z *= di; acc.w *= di;
        // dense for all 4 nodes at once: out4(lane) = b4 + sum_k a[g][k]*W4[k][f]
        float4 out = b4;
#pragma unroll
        for (int k = 0; k < HIDDEN; ++k) {
            float srcval = (k & 3) == 0 ? acc.x : (k & 3) == 1 ? acc.y : (k & 3) == 2 ? acc.z : acc.w;
            float ak = __shfl(srcval, gbase + (k >> 2));
            float4 w4 = sW4[k][f];
            out.x += ak * w4.x; out.y += ak * w4.y; out.z += ak * w4.z; out.w += ak * w4.w;
        }
        out.x = fmaxf(out.x, 0.f) * di;
        out.y = fmaxf(out.y, 0.f) * di;
        out.z = fmaxf(out.z, 0.f) * di;
        out.w = fmaxf(out.w, 0.f) * di;
        *(float4*)&houts[n * HIDDEN + f * 4] = out;
    }
}

// ============ layer 3: 4 nodes/wave, float4 gather, pool into graph acc ============
__global__ __launch_bounds__(256) void k_layer3(const float* __restrict__ hs,
                                                const float* __restrict__ dinv,
                                                const int* __restrict__ offs,
                                                const int* __restrict__ deg,
                                                const int* __restrict__ csr_src,
                                                const int* __restrict__ batch,
                                                float* __restrict__ gpre,
                                                int* __restrict__ gcnt) {
    int lane = threadIdx.x & 63;
    int f = lane & 15;
    int gbase = lane & 48;
    int wid = (blockIdx.x * 256 + threadIdx.x) >> 6;
    int nwaves = gridDim.x * 4;
    for (int quad = wid; quad < NQUADS; quad += nwaves) {
        int n = quad * 4 + (lane >> 4);
        int start = offs[n], dn = deg[n];
        int maxd = max(max(__shfl(dn, 0), __shfl(dn, 16)),
                       max(__shfl(dn, 32), __shfl(dn, 48)));
        float4 acc = make_float4(0.f, 0.f, 0.f, 0.f);
        for (int base = 0; base < maxd; base += 16) {
            int s = csr_src[start + base + f];
            s = (base + f < dn) ? s : N_NODES;
#pragma unroll
            for (int jj = 0; jj < 2; ++jj) {
                float4 v[8];
#pragma unroll
                for (int j = 0; j < 8; ++j) {
                    int sj = __shfl(s, gbase + jj * 8 + j);
                    v[j] = *(const float4*)&hs[sj * HIDDEN + f * 4];
                }
#pragma unroll
                for (int j = 0; j < 8; ++j) {
                    acc.x += v[j].x; acc.y += v[j].y; acc.z += v[j].z; acc.w += v[j].w;
                }
            }
        }
        float di = dinv[n];
        int g = batch[n];
        float* dst = &gpre[g * HIDDEN + f * 4];
        atomicAdd(dst + 0, acc.x * di);
        atomicAdd(dst + 1, acc.y * di);
        atomicAdd(dst + 2, acc.z * di);
        atomicAdd(dst + 3, acc.w * di);
        if (f == 0) atomicAdd(&gcnt[g], 1);
    }
}

// ---------------- final: pooled @ W3 + cnt*b3, @ Wl + bl, softmax ----------------
__global__ __launch_bounds__(256) void k_final(const float* __restrict__ gpre,
                                               const int* __restrict__ gcnt,
                                               const float* __restrict__ W3,
                                               const float* __restrict__ b3,
                                               const float* __restrict__ Wl,
                                               const float* __restrict__ bl,
                                               float* __restrict__ out) {
    int wid = (blockIdx.x * blockDim.x + threadIdx.x) >> 6;
    int lane = threadIdx.x & 63;
    if (wid >= N_GRAPHS) return;
    float pre = gpre[wid * HIDDEN + lane];
    float cnt = (float)gcnt[wid];
    float emb = cnt * b3[lane];
    for (int k = 0; k < HIDDEN; ++k) {
        emb += __shfl(pre, k) * W3[k * HIDDEN + lane];
    }
    float p0 = emb * Wl[lane * 2 + 0];
    float p1 = emb * Wl[lane * 2 + 1];
    for (int d = 32; d > 0; d >>= 1) {
        p0 += __shfl_xor(p0, d);
        p1 += __shfl_xor(p1, d);
    }
    if (lane == 0) {
        float l0 = p0 + bl[0], l1 = p1 + bl[1];
        float m = fmaxf(l0, l1);
        float e0 = __expf(l0 - m), e1 = __expf(l1 - m);
        float inv = 1.f / (e0 + e1);
        out[wid * 2 + 0] = e0 * inv;
        out[wid * 2 + 1] = e1 * inv;
    }
}

extern "C" void kernel_launch(void* const* d_in, const int* in_sizes, int n_in,
                              void* d_out, int out_size, void* d_ws, size_t ws_size,
                              hipStream_t stream) {
    const float* x = (const float*)d_in[0];
    const int* edge = (const int*)d_in[1];
    const int* batch = (const int*)d_in[2];
    const float* W1 = (const float*)d_in[3];
    const float* b1 = (const float*)d_in[4];
    const float* W2 = (const float*)d_in[5];
    const float* b2 = (const float*)d_in[6];
    const float* W3 = (const float*)d_in[7];
    const float* b3 = (const float*)d_in[8];
    const float* Wl = (const float*)d_in[9];
    const float* bl = (const float*)d_in[10];
    float* out = (float*)d_out;

    const int* row = edge;
    const int* col = edge + N_EDGES;

    char* ws = (char*)d_ws;
    size_t off = 0;
    auto alloc = [&](size_t bytes) -> void* {
        void* p = ws + off;
        off = (off + bytes + 255) & ~(size_t)255;
        return p;
    };
    int* deg = (int*)alloc((size_t)N_NODES * 4);
    int* offs = (int*)alloc((size_t)N_NODES * 4);
    int* bsums = (int*)alloc(128 * 4);
    int* cursor = (int*)alloc((size_t)N_NODES * 4);
    float* dinv = (float*)alloc((size_t)N_NODES * 4);
    int* csr_src = (int*)alloc(((size_t)N_EDGES + 256) * 4);  // +pad for speculative reads
    float* xs16 = (float*)alloc((size_t)(N_NODES + 1) * 16 * 4);
    float* h1s = (float*)alloc((size_t)(N_NODES + 1) * HIDDEN * 4);
    float* h2s = (float*)alloc((size_t)(N_NODES + 1) * HIDDEN * 4);
    float* gpre = (float*)alloc((size_t)N_GRAPHS * HIDDEN * 4);
    int* gcnt = (int*)alloc((size_t)N_GRAPHS * 4);

    hipMemsetAsync(deg, 0, (size_t)N_NODES * 4, stream);
    hipMemsetAsync(cursor, 0, (size_t)N_NODES * 4, stream);
    hipMemsetAsync(gpre, 0, (size_t)N_GRAPHS * HIDDEN * 4, stream);
    hipMemsetAsync(gcnt, 0, (size_t)N_GRAPHS * 4, stream);
    // zero gather-sink rows (row N_NODES)
    hipMemsetAsync(h1s + (size_t)N_NODES * HIDDEN, 0, HIDDEN * 4, stream);
    hipMemsetAsync(h2s + (size_t)N_NODES * HIDDEN, 0, HIDDEN * 4, stream);

    const int EB = (N_EDGES + 255) / 256;
    const int NB1024 = (N_NODES + 1023) / 1024;

    k_deg<<<EB, 256, 0, stream>>>(col, deg);
    k_scan_block<<<NB1024, 1024, 0, stream>>>(deg, offs, bsums);
    k_scan_top<<<1, 128, 0, stream>>>(bsums, NB1024);
    k_scan_add<<<NB1024, 1024, 0, stream>>>(offs, bsums);
    k_dinv<<<(N_NODES + 255) / 256, 256, 0, stream>>>(deg, dinv);

    const int NCHUNKS = (N_EDGES + CHUNK_EDGES - 1) / CHUNK_EDGES;
    k_fill<<<NCHUNKS * NRANGES, 256, 0, stream>>>(row, col, offs, cursor, csr_src);
    k_prex<<<((N_NODES + 1) * 16 + 255) / 256, 256, 0, stream>>>(x, dinv, xs16);

    k_layer1<<<LAYER_BLOCKS, 256, 0, stream>>>(xs16, dinv, offs, deg, csr_src, W1, b1, h1s);
    k_layer2<<<LAYER_BLOCKS, 256, 0, stream>>>(h1s, dinv, offs, deg, csr_src, W2, b2, h2s);
    k_layer3<<<LAYER_BLOCKS, 256, 0, stream>>>(h2s, dinv, offs, deg, csr_src, batch, gpre, gcnt);
    k_final<<<(N_GRAPHS * 64 + 255) / 256, 256, 0, stream>>>(gpre, gcnt, W3, b3, Wl, bl, out);
}